// Round 3
// baseline (122.179 us; speedup 1.0000x reference)
//
#include <hip/hip_runtime.h>

// RNN_classifier: L=128 sequential steps over D=262144 independent columns,
// then out[t] = sigmoid(dot(x_bar[t], fc_w) + fc_b), out_size = 128 (fp32).
//
// R3: vec4/thread (1024 single-wave blocks), depth-4 register prefetch,
// per-step dot contribution -> LDS tile, bulk reduce every 16 steps.
// Theory: R1/R2 were issue/overhead-bound, not occupancy-bound.

#define L     128
#define DCOLS 262144
#define TPB   64
#define NBLK  (DCOLS / (4 * TPB))   // 1024 blocks, float4 per thread
#define RS    (DCOLS / 4)           // row stride in float4 units

__device__ __forceinline__ float rcpf(float x) { return __builtin_amdgcn_rcpf(x); }

__device__ __forceinline__ float ftanh(float a) {
    a = fmaxf(a, -15.f);               // only exp(-2a) can overflow
    float e = __expf(-2.f * a);        // v_exp_f32
    float r = rcpf(1.f + e);           // sigmoid(2a)
    return 2.f * r - 1.f;              // tanh(a) = 2*sig(2a) - 1
}

__device__ __forceinline__ float fsig(float z) {
    return rcpf(1.f + __expf(-z));     // inf-safe: 1/(1+inf) = 0
}

__device__ __forceinline__ void upd1(float& h, float& xb, float h0,
                                     float xc, float mc, float wxc,
                                     float wuc, float wgc) {
    float xt = xb + mc * (xc - xb);            // x*m + xb*(1-m)
    float u  = ftanh(xt * wxc);
    float f  = fsig(h + u * wuc) * mc;
    h  = fmaxf(u + f * (h - u), h0);           // h0 + relu(h_t - h0)
    xb = h * wgc + xt;
}

__global__ __launch_bounds__(TPB, 1) void rnn_main(
    const float* __restrict__ x,  const float* __restrict__ wx,
    const float* __restrict__ wg, const float* __restrict__ wu,
    const float* __restrict__ m,  const float* __restrict__ fcw,
    float* __restrict__ part)
{
    __shared__ float tile[16][68];     // stride 68: 16B-aligned rows, 2-way banks
    const int lane = threadIdx.x;
    const int col4 = blockIdx.x * TPB + lane;

    const float4* px  = (const float4*)x  + col4;
    const float4* pm  = (const float4*)m  + col4;
    const float4* pwx = (const float4*)wx + col4;
    const float4* pwu = (const float4*)wu + col4;
    const float4* pwg = (const float4*)wg + col4;
    const float4 fw = ((const float4*)fcw)[col4];

    // ---- t = 0 ----
    float4 x0 = px[0], wx0 = pwx[0], wg0 = pwg[0];
    float4 h0, h, xb;
    h0.x = ftanh(x0.x * wx0.x); h0.y = ftanh(x0.y * wx0.y);
    h0.z = ftanh(x0.z * wx0.z); h0.w = ftanh(x0.w * wx0.w);
    h = h0;
    xb.x = h0.x * wg0.x + x0.x; xb.y = h0.y * wg0.y + x0.y;
    xb.z = h0.z * wg0.z + x0.z; xb.w = h0.w * wg0.w + x0.w;

    // x_bar[0] = x[0]
    tile[0][lane] = x0.x*fw.x + x0.y*fw.y + x0.z*fw.z + x0.w*fw.w;

// bulk reduce of 16 steps x 64 lanes: lane l sums 16 floats of row (l&15),
// quarter (l>>4), then combines quarters with 2 cross-lane swaps.
#define FLUSH(TBASE)                                                        \
    {                                                                       \
        const float4* rp =                                                  \
            (const float4*)(&tile[lane & 15][0] + ((lane >> 4) * 16));      \
        float4 a0 = rp[0], a1 = rp[1], a2 = rp[2], a3 = rp[3];              \
        float p = ((a0.x + a0.y) + (a0.z + a0.w))                           \
                + ((a1.x + a1.y) + (a1.z + a1.w))                           \
                + ((a2.x + a2.y) + (a2.z + a2.w))                           \
                + ((a3.x + a3.y) + (a3.z + a3.w));                          \
        p += __shfl_xor(p, 16, 64);                                         \
        p += __shfl_xor(p, 32, 64);                                         \
        if (lane < 16) part[blockIdx.x * L + (TBASE) + lane] = p;           \
    }

#define STEP(T, BX, BM, BWX, BWU, BWG)                                      \
    {                                                                       \
        tile[(T) & 15][lane] =                                              \
            xb.x*fw.x + xb.y*fw.y + xb.z*fw.z + xb.w*fw.w;                  \
        upd1(h.x, xb.x, h0.x, BX.x, BM.x, BWX.x, BWU.x, BWG.x);             \
        upd1(h.y, xb.y, h0.y, BX.y, BM.y, BWX.y, BWU.y, BWG.y);             \
        upd1(h.z, xb.z, h0.z, BX.z, BM.z, BWX.z, BWU.z, BWG.z);             \
        upd1(h.w, xb.w, h0.w, BX.w, BM.w, BWX.w, BWU.w, BWG.w);             \
        if (((T) & 15) == 15) FLUSH((T) - 15);                              \
    }

    // prefetch rows 1..4 (depth-4, ~20 KB in flight per wave)
    float4 Ax = px[1*RS], Am = pm[1*RS], Awx = pwx[1*RS], Awu = pwu[1*RS], Awg = pwg[1*RS];
    float4 Bx = px[2*RS], Bm = pm[2*RS], Bwx = pwx[2*RS], Bwu = pwu[2*RS], Bwg = pwg[2*RS];
    float4 Cx = px[3*RS], Cm = pm[3*RS], Cwx = pwx[3*RS], Cwu = pwu[3*RS], Cwg = pwg[3*RS];
    float4 Dx = px[4*RS], Dm = pm[4*RS], Dwx = pwx[4*RS], Dwu = pwu[4*RS], Dwg = pwg[4*RS];

    for (int t = 1; t < 122; t += 4) {
        {   // row t from A, prefetch t+4
            float4 cx = Ax, cm = Am, cwx = Awx, cwu = Awu, cwg = Awg;
            long o = (long)((t + 4 > 127) ? 127 : t + 4) * RS;
            Ax = px[o]; Am = pm[o]; Awx = pwx[o]; Awu = pwu[o]; Awg = pwg[o];
            STEP(t, cx, cm, cwx, cwu, cwg);
        }
        {   // row t+1 from B, prefetch t+5
            float4 cx = Bx, cm = Bm, cwx = Bwx, cwu = Bwu, cwg = Bwg;
            long o = (long)((t + 5 > 127) ? 127 : t + 5) * RS;
            Bx = px[o]; Bm = pm[o]; Bwx = pwx[o]; Bwu = pwu[o]; Bwg = pwg[o];
            STEP(t + 1, cx, cm, cwx, cwu, cwg);
        }
        {   // row t+2 from C, prefetch t+6
            float4 cx = Cx, cm = Cm, cwx = Cwx, cwu = Cwu, cwg = Cwg;
            long o = (long)((t + 6 > 127) ? 127 : t + 6) * RS;
            Cx = px[o]; Cm = pm[o]; Cwx = pwx[o]; Cwu = pwu[o]; Cwg = pwg[o];
            STEP(t + 2, cx, cm, cwx, cwu, cwg);
        }
        {   // row t+3 from D, prefetch t+7
            float4 cx = Dx, cm = Dm, cwx = Dwx, cwu = Dwu, cwg = Dwg;
            long o = (long)((t + 7 > 127) ? 127 : t + 7) * RS;
            Dx = px[o]; Dm = pm[o]; Dwx = pwx[o]; Dwu = pwu[o]; Dwg = pwg[o];
            STEP(t + 3, cx, cm, cwx, cwu, cwg);
        }
    }
    // after loop: A=row125, B=row126, C=row127
    STEP(125, Ax, Am, Awx, Awu, Awg);
    STEP(126, Bx, Bm, Bwx, Bwu, Bwg);
    STEP(127, Cx, Cm, Cwx, Cwu, Cwg);   // triggers FLUSH(112)
#undef STEP
#undef FLUSH
}

__global__ __launch_bounds__(64) void rnn_finish(
    const float* __restrict__ part, const float* __restrict__ fcb,
    float* __restrict__ out)
{
    const int t    = blockIdx.x;   // 0..127
    const int lane = threadIdx.x;  // 64
    float s = 0.f;
#pragma unroll
    for (int i = 0; i < NBLK / 64; ++i) s += part[(i * 64 + lane) * L + t];
#pragma unroll
    for (int o = 32; o > 0; o >>= 1) s += __shfl_xor(s, o, 64);
    if (lane == 0) out[t] = fsig(s + fcb[0]);
}

extern "C" void kernel_launch(void* const* d_in, const int* in_sizes, int n_in,
                              void* d_out, int out_size, void* d_ws, size_t ws_size,
                              hipStream_t stream) {
    // setup_inputs order: x, weight_x, weight_g, weight_u, mask, fc_w, fc_b
    const float* x   = (const float*)d_in[0];
    const float* wx  = (const float*)d_in[1];
    const float* wg  = (const float*)d_in[2];
    const float* wu  = (const float*)d_in[3];
    const float* m   = (const float*)d_in[4];
    const float* fcw = (const float*)d_in[5];
    const float* fcb = (const float*)d_in[6];
    float* out  = (float*)d_out;
    float* part = (float*)d_ws;    // NBLK * L floats = 512 KB

    rnn_main<<<NBLK, TPB, 0, stream>>>(x, wx, wg, wu, m, fcw, part);
    rnn_finish<<<L, 64, 0, stream>>>(part, fcb, out);
}